// Round 2
// baseline (7912.753 us; speedup 1.0000x reference)
//
#include <hip/hip_runtime.h>

#define DI __device__ __forceinline__

using f32x4  = __attribute__((ext_vector_type(4))) float;
using u16x8  = __attribute__((ext_vector_type(8))) unsigned short;
using bf16x8 = __attribute__((ext_vector_type(8))) __bf16;

constexpr int BB = 64;    // batch
constexpr int TT = 512;   // time
constexpr int II = 512;   // input dim
constexpr int HH = 1024;  // hidden
constexpr int G4 = 4096;  // 4*H
constexpr int OO = 512;   // output dim

DI unsigned short f2bf(float f) {
    unsigned int u = __builtin_bit_cast(unsigned int, f);
    u += 0x7fffu + ((u >> 16) & 1u);   // RNE
    return (unsigned short)(u >> 16);
}
DI float bf2f(unsigned short h) {
    unsigned int u = ((unsigned int)h) << 16;
    return __builtin_bit_cast(float, u);
}
DI f32x4 mfma_bf16(u16x8 a, u16x8 b, f32x4 c) {
    return __builtin_amdgcn_mfma_f32_16x16x32_bf16(
        __builtin_bit_cast(bf16x8, a), __builtin_bit_cast(bf16x8, b), c, 0, 0, 0);
}

// ---------------------------------------------------------------- cvt fp32->bf16
__global__ __launch_bounds__(256) void cvt4(const float4* __restrict__ in,
                                            ushort4* __restrict__ out, int n4) {
    int i = blockIdx.x * 256 + threadIdx.x;
    if (i < n4) {
        float4 v = in[i];
        ushort4 o;
        o.x = f2bf(v.x); o.y = f2bf(v.y); o.z = f2bf(v.z); o.w = f2bf(v.w);
        out[i] = o;
    }
}

// ---------------------------------------------------------------- xproj GEMM
// C[rloc, n] = seq_row(rloc) . Wih[n, :] + bih[n] + bhh[n], bf16 out.
// rloc = b*Tc + tl ; seq row = b*TT + t0 + tl. K=II=512, N=G4=4096.
// A is fp32, converted to bf16 during LDS staging.
__global__ __launch_bounds__(256)
void gemm_xproj(const float* __restrict__ seq, const ushort* __restrict__ Wih,
                const float* __restrict__ bih, const float* __restrict__ bhh,
                ushort* __restrict__ xp, int lgTc, int t0) {
    __shared__ ushort As[128 * 40];
    __shared__ ushort Bs[128 * 40];
    const int tid  = threadIdx.x;
    const int lane = tid & 63, wave = tid >> 6;
    const int wm = (wave >> 1) * 64, wn = (wave & 1) * 64;
    const int bn = blockIdx.x * 128;   // x = N tile -> consecutive blocks reuse A panel
    const int bm = blockIdx.y * 128;
    const int l15 = lane & 15, l4 = lane >> 4;

    const int srow = tid >> 1, shalf = tid & 1;   // 128 rows x 2 halves of 16
    const int rloc = bm + srow;
    const int bIdx = rloc >> lgTc, tl = rloc & ((1 << lgTc) - 1);
    const float*  gA = seq + ((size_t)bIdx * TT + t0 + tl) * II + shalf * 16;
    const ushort* gB = Wih + (size_t)(bn + srow) * II + shalf * 16;
    ushort* sA = &As[srow * 40 + shalf * 16];
    ushort* sB = &Bs[srow * 40 + shalf * 16];

    f32x4 acc[4][4] = {};
    alignas(16) float  raf[16];
    alignas(16) ushort rbf[16];

#define LOAD_A(kk)                                                        \
    { const float* p = gA + (kk) * 32;                                    \
      *(float4*)(raf + 0)  = *(const float4*)(p + 0);                     \
      *(float4*)(raf + 4)  = *(const float4*)(p + 4);                     \
      *(float4*)(raf + 8)  = *(const float4*)(p + 8);                     \
      *(float4*)(raf + 12) = *(const float4*)(p + 12); }
#define LOAD_B(kk)                                                        \
    { const ushort* p = gB + (kk) * 32;                                   \
      *(u16x8*)(rbf + 0) = *(const u16x8*)(p + 0);                        \
      *(u16x8*)(rbf + 8) = *(const u16x8*)(p + 8); }

    LOAD_A(0); LOAD_B(0);
    const int nk = II / 32;   // 16
    for (int kk = 0; kk < nk; ++kk) {
        __syncthreads();
        alignas(16) ushort cv[16];
#pragma unroll
        for (int j = 0; j < 16; ++j) cv[j] = f2bf(raf[j]);
        *(u16x8*)(sA + 0) = *(u16x8*)(cv + 0);
        *(u16x8*)(sA + 8) = *(u16x8*)(cv + 8);
        *(u16x8*)(sB + 0) = *(u16x8*)(rbf + 0);
        *(u16x8*)(sB + 8) = *(u16x8*)(rbf + 8);
        __syncthreads();
        if (kk + 1 < nk) { LOAD_A(kk + 1); LOAD_B(kk + 1); }
        u16x8 af[4], bfr[4];
#pragma unroll
        for (int i = 0; i < 4; ++i) {
            af[i]  = *(const u16x8*)&As[(wm + i * 16 + l15) * 40 + l4 * 8];
            bfr[i] = *(const u16x8*)&Bs[(wn + i * 16 + l15) * 40 + l4 * 8];
        }
#pragma unroll
        for (int mi = 0; mi < 4; ++mi)
#pragma unroll
            for (int ni = 0; ni < 4; ++ni)
                acc[mi][ni] = mfma_bf16(af[mi], bfr[ni], acc[mi][ni]);
    }
#undef LOAD_A
#undef LOAD_B

#pragma unroll
    for (int mi = 0; mi < 4; ++mi) {
#pragma unroll
        for (int ni = 0; ni < 4; ++ni) {
            const int row = bm + wm + mi * 16 + l4 * 4;
            const int col = bn + wn + ni * 16 + l15;
            const float bsum = bih[col] + bhh[col];
#pragma unroll
            for (int r = 0; r < 4; ++r)
                xp[(size_t)(row + r) * G4 + col] = f2bf(acc[mi][ni][r] + bsum);
        }
    }
}

// ---------------------------------------------------------------- output GEMM
// out[b*TT + t0 + tl, n] = hsC[rloc, :] . Wout[n, :] + bout[n], fp32 out.
// K=HH=1024, N=OO=512, A bf16.
__global__ __launch_bounds__(256)
void gemm_out(const ushort* __restrict__ hsC, const ushort* __restrict__ Wout,
              const float* __restrict__ bout, float* __restrict__ out,
              int lgTc, int t0) {
    __shared__ ushort As[128 * 40];
    __shared__ ushort Bs[128 * 40];
    const int tid  = threadIdx.x;
    const int lane = tid & 63, wave = tid >> 6;
    const int wm = (wave >> 1) * 64, wn = (wave & 1) * 64;
    const int bn = blockIdx.x * 128;
    const int bm = blockIdx.y * 128;
    const int l15 = lane & 15, l4 = lane >> 4;

    const int srow = tid >> 1, shalf = tid & 1;
    const ushort* gA = hsC  + (size_t)(bm + srow) * HH + shalf * 16;
    const ushort* gB = Wout + (size_t)(bn + srow) * HH + shalf * 16;
    ushort* sA = &As[srow * 40 + shalf * 16];
    ushort* sB = &Bs[srow * 40 + shalf * 16];

    f32x4 acc[4][4] = {};
    u16x8 ra0 = *(const u16x8*)(gA + 0), ra1 = *(const u16x8*)(gA + 8);
    u16x8 rb0 = *(const u16x8*)(gB + 0), rb1 = *(const u16x8*)(gB + 8);

    const int nk = HH / 32;   // 32
    for (int kk = 0; kk < nk; ++kk) {
        __syncthreads();
        *(u16x8*)(sA + 0) = ra0; *(u16x8*)(sA + 8) = ra1;
        *(u16x8*)(sB + 0) = rb0; *(u16x8*)(sB + 8) = rb1;
        __syncthreads();
        if (kk + 1 < nk) {
            const ushort* pa = gA + (kk + 1) * 32;
            const ushort* pb = gB + (kk + 1) * 32;
            ra0 = *(const u16x8*)(pa + 0); ra1 = *(const u16x8*)(pa + 8);
            rb0 = *(const u16x8*)(pb + 0); rb1 = *(const u16x8*)(pb + 8);
        }
        u16x8 af[4], bfr[4];
#pragma unroll
        for (int i = 0; i < 4; ++i) {
            af[i]  = *(const u16x8*)&As[(wm + i * 16 + l15) * 40 + l4 * 8];
            bfr[i] = *(const u16x8*)&Bs[(wn + i * 16 + l15) * 40 + l4 * 8];
        }
#pragma unroll
        for (int mi = 0; mi < 4; ++mi)
#pragma unroll
            for (int ni = 0; ni < 4; ++ni)
                acc[mi][ni] = mfma_bf16(af[mi], bfr[ni], acc[mi][ni]);
    }

    const int Tcm1 = (1 << lgTc) - 1;
#pragma unroll
    for (int mi = 0; mi < 4; ++mi) {
#pragma unroll
        for (int ni = 0; ni < 4; ++ni) {
            const int row = bm + wm + mi * 16 + l4 * 4;
            const int col = bn + wn + ni * 16 + l15;
            const float bs = bout[col];
#pragma unroll
            for (int r = 0; r < 4; ++r) {
                const int rl = row + r;
                const int bIdx = rl >> lgTc, tl = rl & Tcm1;
                out[((size_t)bIdx * TT + t0 + tl) * OO + col] = acc[mi][ni][r] + bs;
            }
        }
    }
}

// ---------------------------------------------------------------- one LSTM timestep
// 64 blocks x 256 thr. Block owns j-slice [j0, j0+16) for ALL 4 gates.
__global__ __launch_bounds__(256)
void lstm_step(const ushort* __restrict__ Whh,   // [4096,1024] bf16
               const ushort* __restrict__ xp,    // [B*Tc,4096] bf16 (biases folded)
               ushort* __restrict__ hprev,       // [64,1024] bf16 (chunk boundary)
               ushort* __restrict__ hsC,         // [B*Tc,1024] bf16
               float* __restrict__ cst,          // [64,1024] fp32
               int Tc, int tl, int tg) {
    __shared__ ushort As[64 * 40];
    __shared__ ushort Bs[64 * 40];
    const int tid  = threadIdx.x;
    const int lane = tid & 63, wave = tid >> 6;
    const int l15 = lane & 15, l4 = lane >> 4;
    const int j0  = blockIdx.x * 16;

    f32x4 acc[4] = {};

    if (tg > 0) {
        const int srow = tid >> 2, sq = tid & 3;  // 64 rows x 4 chunks of 8
        const ushort* hsrc;
        size_t rstride;
        if (tl == 0) { hsrc = hprev; rstride = HH; }
        else         { hsrc = hsC + (size_t)(tl - 1) * HH; rstride = (size_t)Tc * HH; }
        const ushort* gA = hsrc + (size_t)srow * rstride + sq * 8;
        const int grow = (srow >> 4) * HH + j0 + (srow & 15);  // Whh row for (gate, j)
        const ushort* gB = Whh + (size_t)grow * HH + sq * 8;
        ushort* sA = &As[srow * 40 + sq * 8];
        ushort* sB = &Bs[srow * 40 + sq * 8];

        u16x8 ra = *(const u16x8*)gA;
        u16x8 rb = *(const u16x8*)gB;
        for (int kk = 0; kk < 32; ++kk) {
            __syncthreads();
            *(u16x8*)sA = ra;
            *(u16x8*)sB = rb;
            __syncthreads();
            if (kk + 1 < 32) {
                ra = *(const u16x8*)(gA + (kk + 1) * 32);
                rb = *(const u16x8*)(gB + (kk + 1) * 32);
            }
            u16x8 a = *(const u16x8*)&As[(wave * 16 + l15) * 40 + l4 * 8];
#pragma unroll
            for (int g = 0; g < 4; ++g) {
                u16x8 b = *(const u16x8*)&Bs[(g * 16 + l15) * 40 + l4 * 8];
                acc[g] = mfma_bf16(a, b, acc[g]);
            }
        }
    }

    const int j = j0 + l15;
#pragma unroll
    for (int r = 0; r < 4; ++r) {
        const int bb = wave * 16 + l4 * 4 + r;
        const size_t xb = ((size_t)bb * Tc + tl) * G4;
        float pi = acc[0][r] + bf2f(xp[xb + 0 * HH + j]);
        float pf = acc[1][r] + bf2f(xp[xb + 1 * HH + j]);
        float pg = acc[2][r] + bf2f(xp[xb + 2 * HH + j]);
        float po = acc[3][r] + bf2f(xp[xb + 3 * HH + j]);
        float ig = 1.f / (1.f + __expf(-pi));
        float fg = 1.f / (1.f + __expf(-pf));
        float gg = tanhf(pg);
        float og = 1.f / (1.f + __expf(-po));
        float cp = (tg > 0) ? cst[bb * HH + j] : 0.f;
        float cn = fg * cp + ig * gg;
        cst[bb * HH + j] = cn;
        const unsigned short h = f2bf(og * tanhf(cn));
        hsC[((size_t)bb * Tc + tl) * HH + j] = h;
        if (tl == Tc - 1) hprev[bb * HH + j] = h;
    }
}

// ---------------------------------------------------------------- launch
extern "C" void kernel_launch(void* const* d_in, const int* in_sizes, int n_in,
                              void* d_out, int out_size, void* d_ws, size_t ws_size,
                              hipStream_t stream) {
    const float* seq  = (const float*)d_in[0];
    const float* Wih  = (const float*)d_in[1];
    const float* Whh  = (const float*)d_in[2];
    const float* bih  = (const float*)d_in[3];
    const float* bhh  = (const float*)d_in[4];
    const float* Wout = (const float*)d_in[5];
    const float* bout = (const float*)d_in[6];

    constexpr size_t MB = 1u << 20;
    char* ws = (char*)d_ws;
    ushort* wih_bf  = (ushort*)(ws);                       // 4 MB  [4096,512]
    ushort* whh_bf  = (ushort*)(ws + 4 * MB);              // 8 MB  [4096,1024]
    ushort* wout_bf = (ushort*)(ws + 12 * MB);             // 1 MB  [512,1024]
    float*  cst     = (float*) (ws + 13 * MB);             // 256 KB [64,1024]
    ushort* hprev   = (ushort*)(ws + 13 * MB + 262144);    // 128 KB [64,1024]
    char*   dynbase = ws + 14 * MB;

    // largest Tc in {512,...,16} whose chunk buffers fit ws_size
    int Tc = 512, lg = 9;
    while (Tc > 16) {
        size_t need = 14 * MB + (size_t)Tc * BB * (size_t)(G4 + HH) * 2;
        if (need <= ws_size) break;
        Tc >>= 1; --lg;
    }
    ushort* xp  = (ushort*)dynbase;                                    // [B*Tc, 4096]
    ushort* hsC = (ushort*)(dynbase + (size_t)Tc * BB * G4 * 2);       // [B*Tc, 1024]

    auto cvt = [&](const float* in, ushort* o, int n) {
        int n4 = n / 4;
        hipLaunchKernelGGL(cvt4, dim3((n4 + 255) / 256), dim3(256), 0, stream,
                           (const float4*)in, (ushort4*)o, n4);
    };
    cvt(Wih,  wih_bf,  G4 * II);
    cvt(Whh,  whh_bf,  G4 * HH);
    cvt(Wout, wout_bf, OO * HH);

    const int Mloc = BB * Tc;
    for (int t0 = 0; t0 < TT; t0 += Tc) {
        hipLaunchKernelGGL(gemm_xproj, dim3(G4 / 128, Mloc / 128), dim3(256), 0, stream,
                           seq, wih_bf, bih, bhh, xp, lg, t0);
        for (int tl = 0; tl < Tc; ++tl)
            hipLaunchKernelGGL(lstm_step, dim3(64), dim3(256), 0, stream,
                               whh_bf, xp, hprev, hsC, cst, Tc, tl, t0 + tl);
        hipLaunchKernelGGL(gemm_out, dim3(OO / 128, Mloc / 128), dim3(256), 0, stream,
                           hsC, wout_bf, bout, (float*)d_out, lg, t0);
    }
}